// Round 1
// baseline (2898.259 us; speedup 1.0000x reference)
//
#include <hip/hip_runtime.h>
#include <math.h>

#define NN 50000
#define EE 800000
#define NPAIR 200000

__device__ __forceinline__ float leaky(float x){ return x >= 0.f ? x : 0.2f*x; }

// ---------------- degree / norms / CSR build ----------------

__global__ void degree_kernel(const int* __restrict__ src, const int* __restrict__ dst,
                              int* cnt_out, int* cnt_in){
  int i = blockIdx.x*blockDim.x + threadIdx.x;
  if(i < EE){
    atomicAdd(&cnt_out[src[i]], 1);
    atomicAdd(&cnt_in[dst[i]], 1);
  }
}

__global__ void norm_kernel(const int* __restrict__ cnt_out, const int* __restrict__ cnt_in,
                            float* __restrict__ out_norm, float* __restrict__ in_norm){
  int i = blockIdx.x*blockDim.x + threadIdx.x;
  if(i < NN){
    int o = cnt_out[i]; if(o < 1) o = 1;
    int d = cnt_in[i];  if(d < 1) d = 1;
    out_norm[i] = 1.f/sqrtf((float)o);
    in_norm[i]  = 1.f/sqrtf((float)d);
  }
}

// single-block exclusive scan of cnt_in[NN] -> row_off[NN+1]
__global__ void scan_kernel(const int* __restrict__ cnt, int* __restrict__ row_off){
  const int T = 512;
  __shared__ int sums[T];
  int t = threadIdx.x;
  int chunk = (NN + T - 1)/T;
  int base = t*chunk;
  int hi = base + chunk; if(hi > NN) hi = NN;
  int s = 0;
  for(int i = base; i < hi; i++) s += cnt[i];
  sums[t] = s;
  __syncthreads();
  for(int off = 1; off < T; off <<= 1){
    int add = (t >= off) ? sums[t-off] : 0;
    __syncthreads();
    sums[t] += add;
    __syncthreads();
  }
  int run = sums[t] - s;   // exclusive prefix of this thread's chunk
  for(int i = base; i < hi; i++){ row_off[i] = run; run += cnt[i]; }
  if(t == T-1) row_off[NN] = EE;
}

__global__ void bucket_kernel(const int* __restrict__ src, const int* __restrict__ dst,
                              const float* __restrict__ w, const int* __restrict__ row_off,
                              int* fill, int* __restrict__ es, float* __restrict__ ew){
  int i = blockIdx.x*blockDim.x + threadIdx.x;
  if(i < EE){
    int d = dst[i];
    int p = row_off[d] + atomicAdd(&fill[d], 1);
    es[p] = src[i];
    ew[p] = w[i];
  }
}

// ---------------- elementwise ----------------

// t = x * out_norm[row], N x 256 (float4 over N*64)
__global__ void scale_rows_kernel(const float* __restrict__ x, const float* __restrict__ out_norm,
                                  float* __restrict__ t){
  int i = blockIdx.x*blockDim.x + threadIdx.x;
  if(i < NN*64){
    int row = i >> 6;
    float s = out_norm[row];
    float4 v = ((const float4*)x)[i];
    v.x *= s; v.y *= s; v.z *= s; v.w *= s;
    ((float4*)t)[i] = v;
  }
}

// h2 = relu(agg * in_norm[row] + b[col]), N x 256
__global__ void h2_kernel(const float* __restrict__ agg, const float* __restrict__ innorm,
                          const float* __restrict__ b, float* __restrict__ out){
  int i = blockIdx.x*blockDim.x + threadIdx.x;
  if(i < NN*64){
    int row = i >> 6;
    int c4 = (i & 63) << 2;
    float inm = innorm[row];
    float4 v = ((const float4*)agg)[i];
    float4 bb = *(const float4*)&b[c4];
    v.x = fmaxf(v.x*inm + bb.x, 0.f);
    v.y = fmaxf(v.y*inm + bb.y, 0.f);
    v.z = fmaxf(v.z*inm + bb.z, 0.f);
    v.w = fmaxf(v.w*inm + bb.w, 0.f);
    ((float4*)out)[i] = v;
  }
}

// h3 = agg * in_norm[row] + b[col], N x 160 (no relu)
__global__ void h3_kernel(const float* __restrict__ agg, const float* __restrict__ innorm,
                          const float* __restrict__ b, float* __restrict__ out){
  int i = blockIdx.x*blockDim.x + threadIdx.x;
  if(i < NN*40){
    int row = i / 40;
    int c4 = (i - row*40) << 2;
    float inm = innorm[row];
    float4 v = ((const float4*)agg)[i];
    float4 bb = *(const float4*)&b[c4];
    v.x = v.x*inm + bb.x;
    v.y = v.y*inm + bb.y;
    v.z = v.z*inm + bb.z;
    v.w = v.w*inm + bb.w;
    ((float4*)out)[i] = v;
  }
}

// ---------------- aggregation (dst-CSR, no atomics) ----------------

template<int F>
__global__ void agg_kernel(const float* __restrict__ feat, const int* __restrict__ es,
                           const float* __restrict__ ew, const int* __restrict__ row_off,
                           float* __restrict__ out){
  int v = blockIdx.x;
  int f = threadIdx.x;
  if(f >= F) return;
  int s = row_off[v], e = row_off[v+1];
  float acc = 0.f;
  int j = s;
  for(; j + 1 < e; j += 2){
    int u0 = es[j], u1 = es[j+1];
    float w0 = ew[j], w1 = ew[j+1];
    acc += feat[u0*F + f]*w0;
    acc += feat[u1*F + f]*w1;
  }
  if(j < e) acc += feat[es[j]*F + f]*ew[j];
  out[v*F + f] = acc;
}

// ---------------- fp32 tiled GEMM ----------------
// C[N x M] = (PRESCALE ? diag(pre)*A : A) @ B ; EPI: C = relu(C*in_norm[row] + bias[col])
template<bool PRESCALE, bool EPI>
__global__ __launch_bounds__(256) void gemm_kernel(
    const float* __restrict__ A, const float* __restrict__ B, float* __restrict__ C,
    int K, int M, const float* __restrict__ pre,
    const float* __restrict__ innorm, const float* __restrict__ bias){
  __shared__ float As[16][65];   // [k][row], +1 pad kills 4-way conflicts
  __shared__ float Bs[16][64];   // [k][col]
  int tid = threadIdx.x;
  int row0 = blockIdx.x*64, col0 = blockIdx.y*64;
  int arow = tid >> 2, ak = (tid & 3) << 2;
  int brow = tid >> 4, bcol = (tid & 15) << 2;
  int tr = tid >> 4, tc = tid & 15;
  float acc[4][4] = {};
  int grow = row0 + arow;
  float prescale = 1.f;
  if(PRESCALE && grow < NN) prescale = pre[grow];

  for(int k0 = 0; k0 < K; k0 += 16){
    float4 av = make_float4(0.f,0.f,0.f,0.f);
    if(grow < NN) av = *(const float4*)&A[(size_t)grow*K + k0 + ak];
    if(PRESCALE){ av.x *= prescale; av.y *= prescale; av.z *= prescale; av.w *= prescale; }
    As[ak+0][arow] = av.x;
    As[ak+1][arow] = av.y;
    As[ak+2][arow] = av.z;
    As[ak+3][arow] = av.w;
    float4 bv = make_float4(0.f,0.f,0.f,0.f);
    int gcol = col0 + bcol;
    if(gcol + 3 < M) bv = *(const float4*)&B[(size_t)(k0+brow)*M + gcol];
    *(float4*)&Bs[brow][bcol] = bv;
    __syncthreads();
    #pragma unroll
    for(int k = 0; k < 16; k++){
      float a[4];
      #pragma unroll
      for(int i = 0; i < 4; i++) a[i] = As[k][tr*4 + i];
      float4 b4 = *(const float4*)&Bs[k][tc << 2];
      float bb[4] = {b4.x, b4.y, b4.z, b4.w};
      #pragma unroll
      for(int i = 0; i < 4; i++)
        #pragma unroll
        for(int j = 0; j < 4; j++)
          acc[i][j] += a[i]*bb[j];
    }
    __syncthreads();
  }

  #pragma unroll
  for(int i = 0; i < 4; i++){
    int r = row0 + tr*4 + i;
    if(r >= NN) continue;
    float inm = EPI ? innorm[r] : 0.f;
    #pragma unroll
    for(int j = 0; j < 4; j++){
      int c = col0 + tc*4 + j;
      if(c >= M) continue;
      float v = acc[i][j];
      if(EPI){ v = v*inm + bias[c]; v = fmaxf(v, 0.f); }
      C[(size_t)r*M + c] = v;
    }
  }
}

// ---------------- predictor: one wave per pair ----------------

__global__ __launch_bounds__(256) void predictor_kernel(
    const float* __restrict__ h3, const int* __restrict__ ps, const int* __restrict__ pd,
    const int* __restrict__ ns, const int* __restrict__ nd,
    const float* __restrict__ P1, const float* __restrict__ pb1,
    const float* __restrict__ P2, const float* __restrict__ pb2,
    const float* __restrict__ P3, const float* __restrict__ pb3,
    float* __restrict__ out){
  __shared__ float zb[4][160];
  __shared__ float y1b[4][80];
  int wid = threadIdx.x >> 6, lane = threadIdx.x & 63;
  int pair = blockIdx.x*4 + wid;       // grid is exactly 2*NPAIR/4 blocks
  int a, b;
  if(pair < NPAIR){ a = ps[pair]; b = pd[pair]; }
  else            { a = ns[pair-NPAIR]; b = nd[pair-NPAIR]; }
  const float* ra = &h3[(size_t)a*160];
  const float* rb = &h3[(size_t)b*160];
  float* z  = zb[wid];
  float* y1 = y1b[wid];
  for(int i = lane; i < 160; i += 64) z[i] = ra[i]*rb[i];
  __syncthreads();
  // stage 1: y1[80] = leaky(z @ P1 + pb1); lanes cover cols 0..63 and 64..79
  float acc0 = pb1[lane];
  float acc1 = (lane < 16) ? pb1[64 + lane] : 0.f;
  for(int k = 0; k < 160; k++){
    float zk = z[k];
    acc0 += zk * P1[k*80 + lane];
    if(lane < 16) acc1 += zk * P1[k*80 + 64 + lane];
  }
  y1[lane] = leaky(acc0);
  if(lane < 16) y1[64 + lane] = leaky(acc1);
  __syncthreads();
  // stage 2: y2[40] = leaky(y1 @ P2 + pb2)
  float acc2 = 0.f;
  if(lane < 40){
    acc2 = pb2[lane];
    for(int k = 0; k < 80; k++) acc2 += y1[k]*P2[k*40 + lane];
  }
  // stage 3: dot(y2, P3) + pb3
  float v = (lane < 40) ? leaky(acc2)*P3[lane] : 0.f;
  #pragma unroll
  for(int off = 32; off; off >>= 1) v += __shfl_down(v, off);
  if(lane == 0) out[pair] = v + pb3[0];
}

// ---------------- launch ----------------

extern "C" void kernel_launch(void* const* d_in, const int* in_sizes, int n_in,
                              void* d_out, int out_size, void* d_ws, size_t ws_size,
                              hipStream_t stream) {
  const float* x  = (const float*)d_in[0];
  const float* w  = (const float*)d_in[1];
  const int* src  = (const int*)d_in[2];
  const int* dst  = (const int*)d_in[3];
  const int* ps   = (const int*)d_in[4];
  const int* pd   = (const int*)d_in[5];
  const int* ns   = (const int*)d_in[6];
  const int* nd   = (const int*)d_in[7];
  const float* W1 = (const float*)d_in[8];  const float* b1  = (const float*)d_in[9];
  const float* W2 = (const float*)d_in[10]; const float* b2  = (const float*)d_in[11];
  const float* W3 = (const float*)d_in[12]; const float* b3  = (const float*)d_in[13];
  const float* P1 = (const float*)d_in[14]; const float* pb1 = (const float*)d_in[15];
  const float* P2 = (const float*)d_in[16]; const float* pb2 = (const float*)d_in[17];
  const float* P3 = (const float*)d_in[18]; const float* pb3 = (const float*)d_in[19];
  float* out = (float*)d_out;

  char* p = (char*)d_ws;
  auto alloc = [&](size_t bytes)->char*{
    char* r = p; p += (bytes + 255) & ~(size_t)255; return r;
  };
  int*   cnt_out = (int*)  alloc(NN*4);          // these three must stay contiguous
  int*   cnt_in  = (int*)  alloc(NN*4);          // (zeroed with one memset)
  int*   fill    = (int*)  alloc(NN*4);
  int*   row_off = (int*)  alloc((NN+1)*4);
  float* out_nrm = (float*)alloc(NN*4);
  float* in_nrm  = (float*)alloc(NN*4);
  int*   es      = (int*)  alloc((size_t)EE*4);
  float* ew      = (float*)alloc((size_t)EE*4);
  float* bufA    = (float*)alloc((size_t)NN*512*4);  // h1 (N x 512), later agg3
  float* bufB    = (float*)alloc((size_t)NN*256*4);  // scaled/projected feats
  float* bufC    = (float*)alloc((size_t)NN*256*4);  // aggregation outputs

  size_t cntPad = (NN*4 + 255) & ~(size_t)255;
  hipMemsetAsync(cnt_out, 0, 3*cntPad, stream);

  degree_kernel<<<(EE+255)/256, 256, 0, stream>>>(src, dst, cnt_out, cnt_in);
  norm_kernel<<<(NN+255)/256, 256, 0, stream>>>(cnt_out, cnt_in, out_nrm, in_nrm);
  scan_kernel<<<1, 512, 0, stream>>>(cnt_in, row_off);
  bucket_kernel<<<(EE+255)/256, 256, 0, stream>>>(src, dst, w, row_off, fill, es, ew);

  // layer 1: aggregate(x*out_norm) @ W1, epilogue: *in_norm + b1, relu
  scale_rows_kernel<<<(NN*64+255)/256, 256, 0, stream>>>(x, out_nrm, bufB);
  agg_kernel<256><<<NN, 256, 0, stream>>>(bufB, es, ew, row_off, bufC);
  dim3 g1((NN+63)/64, (512+63)/64);
  gemm_kernel<false, true><<<g1, 256, 0, stream>>>(bufC, W1, bufA, 256, 512, nullptr, in_nrm, b1);

  // layer 2: aggregate((h1*out_norm) @ W2), then relu(*in_norm + b2)
  dim3 g2((NN+63)/64, (256+63)/64);
  gemm_kernel<true, false><<<g2, 256, 0, stream>>>(bufA, W2, bufB, 512, 256, out_nrm, nullptr, nullptr);
  agg_kernel<256><<<NN, 256, 0, stream>>>(bufB, es, ew, row_off, bufC);
  h2_kernel<<<(NN*64+255)/256, 256, 0, stream>>>(bufC, in_nrm, b2, bufB);

  // layer 3: aggregate((h2*out_norm) @ W3), then *in_norm + b3 -> d_out h region
  dim3 g3((NN+63)/64, (160+63)/64);
  gemm_kernel<true, false><<<g3, 256, 0, stream>>>(bufB, W3, bufC, 256, 160, out_nrm, nullptr, nullptr);
  agg_kernel<160><<<NN, 192, 0, stream>>>(bufC, es, ew, row_off, bufA);
  h3_kernel<<<(NN*40+255)/256, 256, 0, stream>>>(bufA, in_nrm, b3, out + 2*NPAIR);

  // predictor on pos+neg pairs
  predictor_kernel<<<(2*NPAIR)/4, 256, 0, stream>>>(out + 2*NPAIR, ps, pd, ns, nd,
                                                    P1, pb1, P2, pb2, P3, pb3, out);
}

// Round 2
// 1408.201 us; speedup vs baseline: 2.0581x; 2.0581x over previous
//
#include <hip/hip_runtime.h>
#include <math.h>

#define NN 50000
#define EE 800000
#define NPAIR 200000

__device__ __forceinline__ float leaky(float x){ return x >= 0.f ? x : 0.2f*x; }

// ---------------- degree / norms / CSR build ----------------

__global__ void degree_kernel(const int* __restrict__ src, const int* __restrict__ dst,
                              int* cnt_out, int* cnt_in){
  int i = blockIdx.x*blockDim.x + threadIdx.x;
  if(i < EE){
    atomicAdd(&cnt_out[src[i]], 1);
    atomicAdd(&cnt_in[dst[i]], 1);
  }
}

__global__ void norm_kernel(const int* __restrict__ cnt_out, const int* __restrict__ cnt_in,
                            float* __restrict__ out_norm, float* __restrict__ in_norm){
  int i = blockIdx.x*blockDim.x + threadIdx.x;
  if(i < NN){
    int o = cnt_out[i]; if(o < 1) o = 1;
    int d = cnt_in[i];  if(d < 1) d = 1;
    out_norm[i] = 1.f/sqrtf((float)o);
    in_norm[i]  = 1.f/sqrtf((float)d);
  }
}

// single-block exclusive scan of cnt_in[NN] -> row_off[NN+1]
__global__ void scan_kernel(const int* __restrict__ cnt, int* __restrict__ row_off){
  const int T = 512;
  __shared__ int sums[T];
  int t = threadIdx.x;
  int chunk = (NN + T - 1)/T;
  int base = t*chunk;
  int hi = base + chunk; if(hi > NN) hi = NN;
  int s = 0;
  for(int i = base; i < hi; i++) s += cnt[i];
  sums[t] = s;
  __syncthreads();
  for(int off = 1; off < T; off <<= 1){
    int add = (t >= off) ? sums[t-off] : 0;
    __syncthreads();
    sums[t] += add;
    __syncthreads();
  }
  int run = sums[t] - s;   // exclusive prefix of this thread's chunk
  for(int i = base; i < hi; i++){ row_off[i] = run; run += cnt[i]; }
  if(t == T-1) row_off[NN] = EE;
}

__global__ void bucket_kernel(const int* __restrict__ src, const int* __restrict__ dst,
                              const float* __restrict__ w, const int* __restrict__ row_off,
                              int* fill, int* __restrict__ es, float* __restrict__ ew){
  int i = blockIdx.x*blockDim.x + threadIdx.x;
  if(i < EE){
    int d = dst[i];
    int p = row_off[d] + atomicAdd(&fill[d], 1);
    es[p] = src[i];
    ew[p] = w[i];
  }
}

// ---------------- elementwise ----------------

// t = x * out_norm[row], N x 256 (float4 over N*64)
__global__ void scale_rows_kernel(const float* __restrict__ x, const float* __restrict__ out_norm,
                                  float* __restrict__ t){
  int i = blockIdx.x*blockDim.x + threadIdx.x;
  if(i < NN*64){
    int row = i >> 6;
    float s = out_norm[row];
    float4 v = ((const float4*)x)[i];
    v.x *= s; v.y *= s; v.z *= s; v.w *= s;
    ((float4*)t)[i] = v;
  }
}

// h2 = relu(agg * in_norm[row] + b[col]), N x 256
__global__ void h2_kernel(const float* __restrict__ agg, const float* __restrict__ innorm,
                          const float* __restrict__ b, float* __restrict__ out){
  int i = blockIdx.x*blockDim.x + threadIdx.x;
  if(i < NN*64){
    int row = i >> 6;
    int c4 = (i & 63) << 2;
    float inm = innorm[row];
    float4 v = ((const float4*)agg)[i];
    float4 bb = *(const float4*)&b[c4];
    v.x = fmaxf(v.x*inm + bb.x, 0.f);
    v.y = fmaxf(v.y*inm + bb.y, 0.f);
    v.z = fmaxf(v.z*inm + bb.z, 0.f);
    v.w = fmaxf(v.w*inm + bb.w, 0.f);
    ((float4*)out)[i] = v;
  }
}

// h3 = agg * in_norm[row] + b[col], N x 160 (no relu)
__global__ void h3_kernel(const float* __restrict__ agg, const float* __restrict__ innorm,
                          const float* __restrict__ b, float* __restrict__ out){
  int i = blockIdx.x*blockDim.x + threadIdx.x;
  if(i < NN*40){
    int row = i / 40;
    int c4 = (i - row*40) << 2;
    float inm = innorm[row];
    float4 v = ((const float4*)agg)[i];
    float4 bb = *(const float4*)&b[c4];
    v.x = v.x*inm + bb.x;
    v.y = v.y*inm + bb.y;
    v.z = v.z*inm + bb.z;
    v.w = v.w*inm + bb.w;
    ((float4*)out)[i] = v;
  }
}

// ---------------- aggregation (dst-CSR, no atomics) ----------------

template<int F>
__global__ void agg_kernel(const float* __restrict__ feat, const int* __restrict__ es,
                           const float* __restrict__ ew, const int* __restrict__ row_off,
                           float* __restrict__ out){
  int v = blockIdx.x;
  int f = threadIdx.x;
  if(f >= F) return;
  int s = row_off[v], e = row_off[v+1];
  float acc = 0.f;
  int j = s;
  for(; j + 1 < e; j += 2){
    int u0 = es[j], u1 = es[j+1];
    float w0 = ew[j], w1 = ew[j+1];
    acc += feat[u0*F + f]*w0;
    acc += feat[u1*F + f]*w1;
  }
  if(j < e) acc += feat[es[j]*F + f]*ew[j];
  out[v*F + f] = acc;
}

// ---------------- fp32 tiled GEMM ----------------
// C[N x M] = (PRESCALE ? diag(pre)*A : A) @ B ; EPI: C = relu(C*in_norm[row] + bias[col])
template<bool PRESCALE, bool EPI>
__global__ __launch_bounds__(256) void gemm_kernel(
    const float* __restrict__ A, const float* __restrict__ B, float* __restrict__ C,
    int K, int M, const float* __restrict__ pre,
    const float* __restrict__ innorm, const float* __restrict__ bias){
  __shared__ float As[16][65];   // [k][row], +1 pad kills 4-way conflicts
  __shared__ float Bs[16][64];   // [k][col]
  int tid = threadIdx.x;
  int row0 = blockIdx.x*64, col0 = blockIdx.y*64;
  int arow = tid >> 2, ak = (tid & 3) << 2;
  int brow = tid >> 4, bcol = (tid & 15) << 2;
  int tr = tid >> 4, tc = tid & 15;
  float acc[4][4] = {};
  int grow = row0 + arow;
  float prescale = 1.f;
  if(PRESCALE && grow < NN) prescale = pre[grow];

  for(int k0 = 0; k0 < K; k0 += 16){
    float4 av = make_float4(0.f,0.f,0.f,0.f);
    if(grow < NN) av = *(const float4*)&A[(size_t)grow*K + k0 + ak];
    if(PRESCALE){ av.x *= prescale; av.y *= prescale; av.z *= prescale; av.w *= prescale; }
    As[ak+0][arow] = av.x;
    As[ak+1][arow] = av.y;
    As[ak+2][arow] = av.z;
    As[ak+3][arow] = av.w;
    float4 bv = make_float4(0.f,0.f,0.f,0.f);
    int gcol = col0 + bcol;
    if(gcol + 3 < M) bv = *(const float4*)&B[(size_t)(k0+brow)*M + gcol];
    *(float4*)&Bs[brow][bcol] = bv;
    __syncthreads();
    #pragma unroll
    for(int k = 0; k < 16; k++){
      float a[4];
      #pragma unroll
      for(int i = 0; i < 4; i++) a[i] = As[k][tr*4 + i];
      float4 b4 = *(const float4*)&Bs[k][tc << 2];
      float bb[4] = {b4.x, b4.y, b4.z, b4.w};
      #pragma unroll
      for(int i = 0; i < 4; i++)
        #pragma unroll
        for(int j = 0; j < 4; j++)
          acc[i][j] += a[i]*bb[j];
    }
    __syncthreads();
  }

  #pragma unroll
  for(int i = 0; i < 4; i++){
    int r = row0 + tr*4 + i;
    if(r >= NN) continue;
    float inm = EPI ? innorm[r] : 0.f;
    #pragma unroll
    for(int j = 0; j < 4; j++){
      int c = col0 + tc*4 + j;
      if(c >= M) continue;
      float v = acc[i][j];
      if(EPI){ v = v*inm + bias[c]; v = fmaxf(v, 0.f); }
      C[(size_t)r*M + c] = v;
    }
  }
}

// ---------------- predictor v2: fused tiled GEMM, 64 pairs/block ----------------
// LDS (51200 B, reused across phases; 3 blocks/CU):
//   phase A: z^T [160][64] @0 (40960 B), P1 k-panel [32][80] @40960 (10240 B)
//   phase B: y1^T [80][65] @0 (20800 B), P2 [80][40] @20800 (12800 B),
//            y2^T [40][65] @33600 (10400 B)
__global__ __launch_bounds__(256) void predictor_kernel(
    const float* __restrict__ h3, const int* __restrict__ ps, const int* __restrict__ pd,
    const int* __restrict__ ns, const int* __restrict__ nd,
    const float* __restrict__ P1, const float* __restrict__ pb1,
    const float* __restrict__ P2, const float* __restrict__ pb2,
    const float* __restrict__ P3, const float* __restrict__ pb3,
    float* __restrict__ out){
  __shared__ float smem[12800];
  float* z   = smem;            // [160][64] k-major (rows 256 B -> b128-aligned)
  float* p1p = smem + 10240;    // [32][80]
  float* y1  = smem;            // [80][65]
  float* p2  = smem + 5200;     // [80][40]
  float* y2  = smem + 8400;     // [40][65]
  int tid = threadIdx.x;
  int pair0 = blockIdx.x*64;    // grid = 2*NPAIR/64 exactly

  // --- gather h3 rows, z[k][p] = ha[k]*hb[k] (transposed store) ---
  {
    int p = tid >> 2, sub = tid & 3;
    int q = pair0 + p;
    int a, b;
    if(q < NPAIR){ a = ps[q]; b = pd[q]; }
    else         { a = ns[q-NPAIR]; b = nd[q-NPAIR]; }
    const float4* ra = (const float4*)(h3 + (size_t)a*160) + sub*10;
    const float4* rb = (const float4*)(h3 + (size_t)b*160) + sub*10;
    int kbase = sub*40;
    #pragma unroll
    for(int it = 0; it < 10; it++){
      float4 va = ra[it], vb = rb[it];
      int k = kbase + it*4;
      z[(k+0)*64 + p] = va.x*vb.x;
      z[(k+1)*64 + p] = va.y*vb.y;
      z[(k+2)*64 + p] = va.z*vb.z;
      z[(k+3)*64 + p] = va.w*vb.w;
    }
  }

  // --- stage 1: y1[64 pairs][80 cols] = leaky(z @ P1 + pb1) ---
  int tr = tid >> 4, tc = tid & 15;       // thread: pairs tr*4..+3, cols tc+16j
  float acc1[4][5];
  #pragma unroll
  for(int j = 0; j < 5; j++){
    float bv = pb1[tc + 16*j];
    #pragma unroll
    for(int i = 0; i < 4; i++) acc1[i][j] = bv;
  }
  for(int k0 = 0; k0 < 160; k0 += 32){
    __syncthreads();                       // z ready / p1p free
    const float4* gp = (const float4*)(P1 + k0*80);
    for(int i = tid; i < 640; i += 256) ((float4*)p1p)[i] = gp[i];
    __syncthreads();
    #pragma unroll 8
    for(int kk = 0; kk < 32; kk++){
      float4 av = *(const float4*)&z[(k0+kk)*64 + tr*4];
      float a0 = av.x, a1 = av.y, a2 = av.z, a3 = av.w;
      float b[5];
      #pragma unroll
      for(int j = 0; j < 5; j++) b[j] = p1p[kk*80 + tc + 16*j];
      #pragma unroll
      for(int j = 0; j < 5; j++){
        acc1[0][j] += a0*b[j];
        acc1[1][j] += a1*b[j];
        acc1[2][j] += a2*b[j];
        acc1[3][j] += a3*b[j];
      }
    }
  }
  __syncthreads();                          // all z reads done; region reusable

  // write y1^T (padded 65 to break bank conflicts), stage P2
  #pragma unroll
  for(int i = 0; i < 4; i++)
    #pragma unroll
    for(int j = 0; j < 5; j++)
      y1[(tc + 16*j)*65 + tr*4 + i] = leaky(acc1[i][j]);
  for(int i = tid; i < 800; i += 256) ((float4*)p2)[i] = ((const float4*)P2)[i];
  __syncthreads();

  // --- stage 2: y2[64][40] = leaky(y1 @ P2 + pb2); thread: 2 pairs x 5 cols ---
  int tr2 = tid >> 3, tc2 = tid & 7;       // pairs tr2*2..+1, cols tc2+8j
  float acc2[2][5];
  #pragma unroll
  for(int j = 0; j < 5; j++){
    float bv = pb2[tc2 + 8*j];
    acc2[0][j] = bv; acc2[1][j] = bv;
  }
  #pragma unroll 4
  for(int k = 0; k < 80; k++){
    float a0 = y1[k*65 + tr2*2], a1 = y1[k*65 + tr2*2 + 1];
    #pragma unroll
    for(int j = 0; j < 5; j++){
      float bv = p2[k*40 + tc2 + 8*j];
      acc2[0][j] += a0*bv;
      acc2[1][j] += a1*bv;
    }
  }
  #pragma unroll
  for(int i = 0; i < 2; i++)
    #pragma unroll
    for(int j = 0; j < 5; j++)
      y2[(tc2 + 8*j)*65 + tr2*2 + i] = leaky(acc2[i][j]);
  __syncthreads();

  // --- stage 3: out[p] = y2[p] . P3 + pb3 ---
  if(tid < 64){
    float s = pb3[0];
    #pragma unroll 8
    for(int k = 0; k < 40; k++) s += y2[k*65 + tid]*P3[k];
    out[pair0 + tid] = s;
  }
}

// ---------------- launch ----------------

extern "C" void kernel_launch(void* const* d_in, const int* in_sizes, int n_in,
                              void* d_out, int out_size, void* d_ws, size_t ws_size,
                              hipStream_t stream) {
  const float* x  = (const float*)d_in[0];
  const float* w  = (const float*)d_in[1];
  const int* src  = (const int*)d_in[2];
  const int* dst  = (const int*)d_in[3];
  const int* ps   = (const int*)d_in[4];
  const int* pd   = (const int*)d_in[5];
  const int* ns   = (const int*)d_in[6];
  const int* nd   = (const int*)d_in[7];
  const float* W1 = (const float*)d_in[8];  const float* b1  = (const float*)d_in[9];
  const float* W2 = (const float*)d_in[10]; const float* b2  = (const float*)d_in[11];
  const float* W3 = (const float*)d_in[12]; const float* b3  = (const float*)d_in[13];
  const float* P1 = (const float*)d_in[14]; const float* pb1 = (const float*)d_in[15];
  const float* P2 = (const float*)d_in[16]; const float* pb2 = (const float*)d_in[17];
  const float* P3 = (const float*)d_in[18]; const float* pb3 = (const float*)d_in[19];
  float* out = (float*)d_out;

  char* p = (char*)d_ws;
  auto alloc = [&](size_t bytes)->char*{
    char* r = p; p += (bytes + 255) & ~(size_t)255; return r;
  };
  int*   cnt_out = (int*)  alloc(NN*4);          // these three must stay contiguous
  int*   cnt_in  = (int*)  alloc(NN*4);          // (zeroed with one memset)
  int*   fill    = (int*)  alloc(NN*4);
  int*   row_off = (int*)  alloc((NN+1)*4);
  float* out_nrm = (float*)alloc(NN*4);
  float* in_nrm  = (float*)alloc(NN*4);
  int*   es      = (int*)  alloc((size_t)EE*4);
  float* ew      = (float*)alloc((size_t)EE*4);
  float* bufA    = (float*)alloc((size_t)NN*512*4);  // h1 (N x 512), later agg3
  float* bufB    = (float*)alloc((size_t)NN*256*4);  // scaled/projected feats
  float* bufC    = (float*)alloc((size_t)NN*256*4);  // aggregation outputs

  size_t cntPad = (NN*4 + 255) & ~(size_t)255;
  hipMemsetAsync(cnt_out, 0, 3*cntPad, stream);

  degree_kernel<<<(EE+255)/256, 256, 0, stream>>>(src, dst, cnt_out, cnt_in);
  norm_kernel<<<(NN+255)/256, 256, 0, stream>>>(cnt_out, cnt_in, out_nrm, in_nrm);
  scan_kernel<<<1, 512, 0, stream>>>(cnt_in, row_off);
  bucket_kernel<<<(EE+255)/256, 256, 0, stream>>>(src, dst, w, row_off, fill, es, ew);

  // layer 1: aggregate(x*out_norm) @ W1, epilogue: *in_norm + b1, relu
  scale_rows_kernel<<<(NN*64+255)/256, 256, 0, stream>>>(x, out_nrm, bufB);
  agg_kernel<256><<<NN, 256, 0, stream>>>(bufB, es, ew, row_off, bufC);
  dim3 g1((NN+63)/64, (512+63)/64);
  gemm_kernel<false, true><<<g1, 256, 0, stream>>>(bufC, W1, bufA, 256, 512, nullptr, in_nrm, b1);

  // layer 2: aggregate((h1*out_norm) @ W2), then relu(*in_norm + b2)
  dim3 g2((NN+63)/64, (256+63)/64);
  gemm_kernel<true, false><<<g2, 256, 0, stream>>>(bufA, W2, bufB, 512, 256, out_nrm, nullptr, nullptr);
  agg_kernel<256><<<NN, 256, 0, stream>>>(bufB, es, ew, row_off, bufC);
  h2_kernel<<<(NN*64+255)/256, 256, 0, stream>>>(bufC, in_nrm, b2, bufB);

  // layer 3: aggregate((h2*out_norm) @ W3), then *in_norm + b3 -> d_out h region
  dim3 g3((NN+63)/64, (160+63)/64);
  gemm_kernel<true, false><<<g3, 256, 0, stream>>>(bufB, W3, bufC, 256, 160, out_nrm, nullptr, nullptr);
  agg_kernel<160><<<NN, 192, 0, stream>>>(bufC, es, ew, row_off, bufA);
  h3_kernel<<<(NN*40+255)/256, 256, 0, stream>>>(bufA, in_nrm, b3, out + 2*NPAIR);

  // predictor on pos+neg pairs
  predictor_kernel<<<(2*NPAIR)/64, 256, 0, stream>>>(out + 2*NPAIR, ps, pd, ns, nd,
                                                     P1, pb1, P2, pb2, P3, pb3, out);
}